// Round 9
// baseline (596.371 us; speedup 1.0000x reference)
//
#include <hip/hip_runtime.h>

// Problem constants (B=4, N=8192, D=1024, H=16, hd=64, G=512)
#define BB 4
#define NN 8192
#define DD 1024
#define HH 16
#define HD 64
#define GG 512

typedef short short8 __attribute__((ext_vector_type(8)));
typedef float f32x4 __attribute__((ext_vector_type(4)));
typedef int int4v __attribute__((ext_vector_type(4)));
typedef int int8v __attribute__((ext_vector_type(8)));

__device__ __forceinline__ unsigned short f2bf(float f) {
  union { float f; unsigned int u; } v; v.f = f;
  unsigned int r = v.u + 0x7FFFu + ((v.u >> 16) & 1u);
  return (unsigned short)(r >> 16);
}
__device__ __forceinline__ float bf2f(unsigned short b) {
  union { unsigned int u; float f; } v; v.u = ((unsigned int)b) << 16;
  return v.f;
}

// Async global->LDS 16B copy: LDS dest = wave-uniform base + lane*16 (m104);
// global src is per-lane (m173).
__device__ __forceinline__ void gload16(const void* g, void* l) {
  __builtin_amdgcn_global_load_lds((const __attribute__((address_space(1))) void*)g,
                                   (__attribute__((address_space(3))) void*)l,
                                   16, 0, 0);
}

// Merged f32->bf16 convert: x (8,388,608 float4) then Wv/Wout (262,144 each).
__global__ void cvt_all(const float* __restrict__ x, const float* __restrict__ Wqkv,
                        const float* __restrict__ Wout,
                        unsigned short* __restrict__ xb,
                        unsigned short* __restrict__ wvb, unsigned short* __restrict__ woutb) {
  const int total = 8388608 + 2 * 262144;
  int stride = gridDim.x * blockDim.x;
  for (int j = blockIdx.x * blockDim.x + threadIdx.x; j < total; j += stride) {
    const float4* s; ushort4* d; int r;
    if (j < 8388608) { s = (const float4*)x; d = (ushort4*)xb; r = j; }
    else {
      int q = j - 8388608; int seg = q >> 18; r = q & 262143;
      if (seg == 0) { s = (const float4*)(Wqkv + 2097152); d = (ushort4*)wvb; }
      else          { s = (const float4*)Wout;             d = (ushort4*)woutb; }
    }
    float4 f = s[r];
    ushort4 u;
    u.x = f2bf(f.x); u.y = f2bf(f.y); u.z = f2bf(f.z); u.w = f2bf(f.w);
    d[r] = u;
  }
}

// Build fp8 operands for the k-norm GEMM, K padded 1024->1152:
//   xb8 row n:  [fp8(x_n), fp8(1.0), 0 x 127]
//   wk8 row d:  [fp8(32*Wk[d]), fp8(32*bk[d]), 0 x 127]
// Augmented column folds the bias into the MFMA: acc = 32*(k+b).
__global__ __launch_bounds__(256) void cvt8_kernel(
    const unsigned short* __restrict__ xb, const float* __restrict__ Wqkv,
    const float* __restrict__ bqkv,
    unsigned char* __restrict__ xb8, unsigned char* __restrict__ wk8) {
  int r = blockIdx.x;                       // 0..33791 (32768 x-rows + 1024 Wk-rows)
  bool isX = r < 32768;
  unsigned char* dst = isX ? xb8 + (size_t)r * 1152
                           : wk8 + (size_t)(r - 32768) * 1152;
  for (int c = threadIdx.x; c < 288; c += 256) {
    unsigned int word = 0;
    if (c < 256) {
      float f0, f1, f2, f3;
      if (isX) {
        ushort4 v = *(const ushort4*)(xb + (size_t)r * 1024 + c * 4);
        f0 = bf2f(v.x); f1 = bf2f(v.y); f2 = bf2f(v.z); f3 = bf2f(v.w);
      } else {
        const float* wr = Wqkv + 1048576 + (size_t)(r - 32768) * 1024 + c * 4;
        f0 = wr[0] * 32.0f; f1 = wr[1] * 32.0f; f2 = wr[2] * 32.0f; f3 = wr[3] * 32.0f;
      }
      word = __builtin_amdgcn_cvt_pk_fp8_f32(f0, f1, word, false);
      word = __builtin_amdgcn_cvt_pk_fp8_f32(f2, f3, word, true);
    } else if (c == 256) {
      float f0 = isX ? 1.0f : 32.0f * bqkv[1024 + (r - 32768)];
      word = __builtin_amdgcn_cvt_pk_fp8_f32(f0, 0.0f, 0, false);
    }
    *(unsigned int*)(dst + c * 4) = word;
  }
}

// ========== MX-fp8 k-norm GEMM: kw[n,h] = ||k_n_h + bk_h|| ==========
// 256x256 tile, BK=128 fp8 bytes, 9 K-tiles (K=1152), ring-2 LDS (128 KB),
// counted vmcnt(8), slot^(row&7) XOR swizzle (2 lanes/bank = free).
// acc = 32*(k+b) (bias via augmented column); epilogue: sqrt(sum (acc/32)^2).
// Norms are invariant to within-head col permutation -> fragment-layout-proof.
__global__ __launch_bounds__(512, 2) void gemm_knorm8(
    const unsigned char* __restrict__ A,   // xb8: M x 1152
    const unsigned char* __restrict__ Bm,  // wk8: 1024 x 1152
    float* __restrict__ Cout, int M) {
  __shared__ __align__(16) unsigned char smem[2][2][32768];  // [ring][A|B][256*128]

  const int t512 = threadIdx.x;
  const int wv = t512 >> 6, lane = t512 & 63;
  const int wm = wv >> 2, wn = wv & 3;
  const int l15 = lane & 15, sr = lane >> 4;

  // XCD-aware bijective swizzle (grid = 512, %8==0)
  const int nwg = gridDim.x;
  const int lin = blockIdx.x;
  const int swz = (lin & 7) * (nwg >> 3) + (lin >> 3);
  const int bm = (swz >> 2) * 256;          // 128 m-blocks
  const int bn = (swz & 3) * 256;           // 4 n-blocks

  // staging: wave wv covers rows [wv*32, wv*32+32), 4 gloads of 8 rows x 8 slots.
  // phys slot p of row r holds global slot p ^ (r&7).
  const int rrl = lane >> 3;                // row within 8-row gload
  const int ps  = lane & 7;                 // phys 16B slot

  auto stage = [&](int t, int q) {
    #pragma unroll
    for (int it = 0; it < 4; ++it) {
      int ra = wv * 32 + it * 8 + rrl;
      int gs = ps ^ (ra & 7);
      gload16(A + (size_t)(bm + ra) * 1152 + t * 128 + gs * 16,
              &smem[q][0][(wv * 32 + it * 8) * 128]);
      gload16(Bm + (size_t)(bn + ra) * 1152 + t * 128 + gs * 16,
              &smem[q][1][(wv * 32 + it * 8) * 128]);
    }
  };

  // fragment LDS byte offsets (swizzled): frag = 32 bytes = 2 x 16B slots
  int aOff[8][2], bOff[4][2];
  #pragma unroll
  for (int i = 0; i < 8; ++i) {
    int r = wm * 128 + i * 16 + l15;
    #pragma unroll
    for (int h = 0; h < 2; ++h)
      aOff[i][h] = r * 128 + (((sr * 2 + h) ^ (r & 7)) * 16);
  }
  #pragma unroll
  for (int j = 0; j < 4; ++j) {
    int r = wn * 64 + j * 16 + l15;
    #pragma unroll
    for (int h = 0; h < 2; ++h)
      bOff[j][h] = r * 128 + (((sr * 2 + h) ^ (r & 7)) * 16);
  }

  f32x4 acc[8][4] = {};

  stage(0, 0); stage(1, 1);

  for (int t = 0; t < 9; ++t) {
    if (t < 8) asm volatile("s_waitcnt vmcnt(8)" ::: "memory");
    else       asm volatile("s_waitcnt vmcnt(0)" ::: "memory");
    __builtin_amdgcn_s_barrier();            // tile t resident in buf t&1

    const unsigned char* ab = smem[t & 1][0];
    const unsigned char* bb = smem[t & 1][1];
    int8v b8[4];
    #pragma unroll
    for (int j = 0; j < 4; ++j) {
      int4v lo = *(const int4v*)(bb + bOff[j][0]);
      int4v hi = *(const int4v*)(bb + bOff[j][1]);
      int8v v; v[0]=lo[0]; v[1]=lo[1]; v[2]=lo[2]; v[3]=lo[3];
               v[4]=hi[0]; v[5]=hi[1]; v[6]=hi[2]; v[7]=hi[3];
      b8[j] = v;
    }
    __builtin_amdgcn_s_setprio(1);
    #pragma unroll
    for (int i = 0; i < 8; ++i) {
      int4v lo = *(const int4v*)(ab + aOff[i][0]);
      int4v hi = *(const int4v*)(ab + aOff[i][1]);
      int8v a8; a8[0]=lo[0]; a8[1]=lo[1]; a8[2]=lo[2]; a8[3]=lo[3];
                a8[4]=hi[0]; a8[5]=hi[1]; a8[6]=hi[2]; a8[7]=hi[3];
      #pragma unroll
      for (int j = 0; j < 4; ++j)
        acc[i][j] = __builtin_amdgcn_mfma_scale_f32_16x16x128_f8f6f4(
            a8, b8[j], acc[i][j], 0, 0, 0, 127, 0, 127);  // fp8/fp8, scales = 1.0
    }
    __builtin_amdgcn_s_setprio(0);
    __builtin_amdgcn_s_barrier();            // all reads of buf t&1 done
    if (t + 2 < 9) stage(t + 2, t & 1);      // safe to overwrite
  }

  // Epilogue: norm over this wave's head. C/D layout col=l15, row=sr*4+r
  // (shape-determined, m121/m127-verified for f8f6f4).
  const int hcol = (bn >> 6) + wn;
  #pragma unroll
  for (int i = 0; i < 8; ++i) {
    #pragma unroll
    for (int r = 0; r < 4; ++r) {
      float s = 0.0f;
      #pragma unroll
      for (int j = 0; j < 4; ++j) {
        float val = acc[i][j][r] * 0.03125f;   // undo x32 weight pre-scale
        s += val * val;
      }
      s += __shfl_xor(s, 1, 64);
      s += __shfl_xor(s, 2, 64);
      s += __shfl_xor(s, 4, 64);
      s += __shfl_xor(s, 8, 64);
      if (l15 == 0) {
        int row = bm + wm * 128 + i * 16 + sr * 4 + r;
        Cout[(size_t)row * 16 + hcol] = sqrtf(s);
      }
    }
  }
}

// xw: per (b,g) bucket, xw[h,:] = sum_{n in g} w[n,h] * x[n,:]; sw[h] = sum w.
__global__ __launch_bounds__(256) void xw_kernel(
    const unsigned short* __restrict__ xb, const float* __restrict__ kw,
    unsigned short* __restrict__ xwb, float* __restrict__ sw) {
  __shared__ float w_l[20][16];
  __shared__ int mflag[20];
  const int bg = blockIdx.x;             // b*512+g
  const int b = bg >> 9, g = bg & 511;
  const int t = threadIdx.x;
  int lo = (g * (NN - 1)) / (GG - 1) - 2;
  if (lo < 0) lo = 0;
  if (t < 20) {
    int n = lo + t;
    // EXACT ref bucket math: trunc((n/8191)*511)
    mflag[t] = (n < NN) && ((int)(((float)n / 8191.0f) * 511.0f) == g);
  }
  for (int u = t; u < 320; u += 256) {
    int ln = u >> 4, h = u & 15;
    int n = lo + ln;
    float w = 0.0f;
    if (n < NN && (int)(((float)n / 8191.0f) * 511.0f) == g)
      w = kw[((size_t)(b * NN + n)) * 16 + h];
    w_l[ln][h] = w;
  }
  __syncthreads();
  if (t < 16) {
    float s = 0.0f;
    #pragma unroll
    for (int ln = 0; ln < 20; ++ln) s += w_l[ln][t];
    sw[bg * 16 + t] = s;
  }
  float acc[16][4] = {};
  const int c0 = t * 4;
  for (int ln = 0; ln < 20; ++ln) {
    if (!mflag[ln]) continue;            // wave-uniform branch
    int n = lo + ln;
    ushort4 xv = *(const ushort4*)(xb + ((size_t)(b * NN + n)) * 1024 + c0);
    float x0 = bf2f(xv.x), x1 = bf2f(xv.y), x2 = bf2f(xv.z), x3 = bf2f(xv.w);
    #pragma unroll
    for (int h = 0; h < 16; ++h) {
      float w = w_l[ln][h];
      acc[h][0] += w * x0; acc[h][1] += w * x1;
      acc[h][2] += w * x2; acc[h][3] += w * x3;
    }
  }
  #pragma unroll
  for (int h = 0; h < 16; ++h) {
    ushort4 o;
    o.x = f2bf(acc[h][0]); o.y = f2bf(acc[h][1]);
    o.z = f2bf(acc[h][2]); o.w = f2bf(acc[h][3]);
    *(ushort4*)(xwb + ((size_t)h * 2048 + bg) * 1024 + c0) = o;
  }
}

// field GEMM: per h, field2[(b,g), h*64+d] = xw_h[(b,g),:] . Wv[h*64+d,:] + sw*bv.
__global__ __launch_bounds__(256, 2) void field_gemm(
    const unsigned short* __restrict__ xwb, const unsigned short* __restrict__ wvb,
    const float* __restrict__ sw, const float* __restrict__ bv,
    float* __restrict__ field2) {
  __shared__ __align__(16) unsigned short As[2][64 * 32];  // 4 KB x2
  __shared__ __align__(16) unsigned short Bs[2][64 * 32];  // 4 KB x2
  const int h = blockIdx.x >> 5;           // 16 h
  const int mb = blockIdx.x & 31;          // 32 m-blocks of 64
  const int t = threadIdx.x;
  const int wv_ = t >> 6, lane = t & 63;
  const int l15 = lane & 15, sr = lane >> 4;

  const unsigned short* Ah = xwb + (size_t)h * 2048 * 1024 + (size_t)mb * 64 * 1024;
  const unsigned short* Bh = wvb + (size_t)h * 64 * 1024;

  const int srow = wv_ * 16 + (lane >> 2);          // 0..63
  const int sg = (lane & 3) ^ ((srow >> 1) & 3);    // swizzled k-segment
  const int dL = wv_ * 1024;                        // wave-uniform LDS bytes

  const unsigned short* aG = Ah + (size_t)srow * 1024 + sg * 8;
  const unsigned short* bG = Bh + (size_t)srow * 1024 + sg * 8;

  auto stage = [&](int tt, int q) {
    gload16(aG + tt * 32, (char*)As[q] + dL);
    gload16(bG + tt * 32, (char*)Bs[q] + dL);
  };

  int aOff, bOff[4];
  {
    int r = wv_ * 16 + l15;
    aOff = r * 64 + ((sr ^ ((r >> 1) & 3)) * 16);
  }
  #pragma unroll
  for (int j = 0; j < 4; ++j) {
    int r = j * 16 + l15;
    bOff[j] = r * 64 + ((sr ^ ((r >> 1) & 3)) * 16);
  }

  f32x4 acc[4] = {};
  stage(0, 0);
  for (int tt = 0; tt < 32; ++tt) {
    if (tt + 1 < 32) {
      stage(tt + 1, (tt + 1) & 1);
      asm volatile("s_waitcnt vmcnt(2)" ::: "memory");  // tile tt landed
    } else {
      asm volatile("s_waitcnt vmcnt(0)" ::: "memory");
    }
    __builtin_amdgcn_s_barrier();
    const char* a = (const char*)As[tt & 1];
    const char* bb = (const char*)Bs[tt & 1];
    short8 aF = *(const short8*)(a + aOff);
    short8 bF[4];
    #pragma unroll
    for (int j = 0; j < 4; ++j) bF[j] = *(const short8*)(bb + bOff[j]);
    #pragma unroll
    for (int j = 0; j < 4; ++j)
      acc[j] = __builtin_amdgcn_mfma_f32_16x16x32_bf16(aF, bF[j], acc[j], 0, 0, 0);
    __builtin_amdgcn_s_barrier();
  }

  const int row0 = mb * 64 + wv_ * 16 + sr * 4;
  #pragma unroll
  for (int r = 0; r < 4; ++r) {
    float swv = sw[(row0 + r) * 16 + h];
    #pragma unroll
    for (int j = 0; j < 4; ++j) {
      int col = h * 64 + j * 16 + l15;
      field2[(size_t)(row0 + r) * 1024 + col] = acc[j][r] + swv * bv[col];
    }
  }
}

// Small out-projection GEMM: 64x64 tile, 512 blocks (full CU coverage).
__global__ __launch_bounds__(256, 4) void gemm64(
    const unsigned short* __restrict__ A, const unsigned short* __restrict__ Bm,
    const float* __restrict__ bias, float* __restrict__ C,
    int M, int N, int K) {
  __shared__ __align__(16) unsigned short As[2][64 * 32];
  __shared__ __align__(16) unsigned short Bs[2][64 * 32];
  const int nb = N >> 6;
  const int mb = blockIdx.x / nb, nk = blockIdx.x % nb;
  const int t = threadIdx.x;
  const int wv_ = t >> 6, lane = t & 63;
  const int l15 = lane & 15, sr = lane >> 4;
  const int nt = K >> 5;

  const unsigned short* Ab = A + (size_t)mb * 64 * K;
  const unsigned short* Bb = Bm + (size_t)nk * 64 * K;

  const int srow = wv_ * 16 + (lane >> 2);
  const int sg = (lane & 3) ^ ((srow >> 1) & 3);
  const int dL = wv_ * 1024;

  const unsigned short* aG = Ab + (size_t)srow * K + sg * 8;
  const unsigned short* bG = Bb + (size_t)srow * K + sg * 8;

  auto stage = [&](int tt, int q) {
    gload16(aG + tt * 32, (char*)As[q] + dL);
    gload16(bG + tt * 32, (char*)Bs[q] + dL);
  };

  int aOff, bOff[4];
  {
    int r = wv_ * 16 + l15;
    aOff = r * 64 + ((sr ^ ((r >> 1) & 3)) * 16);
  }
  #pragma unroll
  for (int j = 0; j < 4; ++j) {
    int r = j * 16 + l15;
    bOff[j] = r * 64 + ((sr ^ ((r >> 1) & 3)) * 16);
  }

  f32x4 acc[4] = {};
  stage(0, 0);
  for (int tt = 0; tt < nt; ++tt) {
    if (tt + 1 < nt) {
      stage(tt + 1, (tt + 1) & 1);
      asm volatile("s_waitcnt vmcnt(2)" ::: "memory");
    } else {
      asm volatile("s_waitcnt vmcnt(0)" ::: "memory");
    }
    __builtin_amdgcn_s_barrier();
    const char* a = (const char*)As[tt & 1];
    const char* bb = (const char*)Bs[tt & 1];
    short8 aF = *(const short8*)(a + aOff);
    short8 bF[4];
    #pragma unroll
    for (int j = 0; j < 4; ++j) bF[j] = *(const short8*)(bb + bOff[j]);
    #pragma unroll
    for (int j = 0; j < 4; ++j)
      acc[j] = __builtin_amdgcn_mfma_f32_16x16x32_bf16(aF, bF[j], acc[j], 0, 0, 0);
    __builtin_amdgcn_s_barrier();
  }

  const int row0 = mb * 64 + wv_ * 16 + sr * 4;
  #pragma unroll
  for (int r = 0; r < 4; ++r) {
    #pragma unroll
    for (int j = 0; j < 4; ++j) {
      int col = nk * 64 + j * 16 + l15;
      C[(size_t)(row0 + r) * N + col] = acc[j][r] + bias[col];
    }
  }
}

// Circular conv along g: out[g] = sum_m w_m in[(g+256+m)&511], w iterative.
__global__ void conv_kernel(const float* __restrict__ field2,
                            unsigned short* __restrict__ fconv2) {
  int i = blockIdx.x * blockDim.x + threadIdx.x;   // 2048*256 float4 units
  int c4 = i & 255;
  int bg = i >> 8;
  int b = bg >> 9, g = bg & 511;
  const float4* f4 = (const float4*)field2;
  float w = 0.86466471f;                           // invZ
  const float dec = 0.13533528f;                   // e^{-2}
  float4 s = {0.f, 0.f, 0.f, 0.f};
  #pragma unroll
  for (int m = 0; m <= 20; ++m) {
    float4 v = f4[(size_t)((b << 9) + ((g + 256 + m) & 511)) * 256 + c4];
    s.x += w * v.x; s.y += w * v.y; s.z += w * v.z; s.w += w * v.w;
    w *= dec;
  }
  ushort4 o;
  o.x = f2bf(s.x); o.y = f2bf(s.y); o.z = f2bf(s.z); o.w = f2bf(s.w);
  *(ushort4*)(fconv2 + (size_t)bg * 1024 + c4 * 4) = o;
}

// Row-expand: out[b,n,:] = small[(b,g(n)),:]
__global__ void expand_kernel(const float* __restrict__ small,
                              float* __restrict__ out) {
  const int total = 32768 * 256;
  int stride = gridDim.x * blockDim.x;
  for (int i = blockIdx.x * blockDim.x + threadIdx.x; i < total; i += stride) {
    int m = i >> 8;
    int b = m >> 13, n = m & (NN - 1);
    int g = (int)(((float)n / 8191.0f) * 511.0f); // exact ref index math
    ((float4*)out)[i] = ((const float4*)small)[(((b << 9) + g) << 8) + (i & 255)];
  }
}

extern "C" void kernel_launch(void* const* d_in, const int* in_sizes, int n_in,
                              void* d_out, int out_size, void* d_ws, size_t ws_size,
                              hipStream_t stream) {
  const float* x    = (const float*)d_in[0];   // (4,8192,1024)
  const float* Wqkv = (const float*)d_in[1];   // (3072,1024)
  const float* bqkv = (const float*)d_in[2];   // (3072,)
  const float* Wout = (const float*)d_in[3];   // (1024,1024)
  const float* bout = (const float*)d_in[4];   // (1024,)
  float* out = (float*)d_out;                  // (4,8192,1024) f32

  const size_t M = (size_t)BB * NN;            // 32768

  // Workspace layout
  char* ws = (char*)d_ws;
  size_t off = 0;
  unsigned short* xb    = (unsigned short*)(ws + off); off += M * DD * 2;            // 64 MB
  unsigned char*  xb8   = (unsigned char*)(ws + off);  off += M * 1152;              // 37.75 MB
  unsigned char*  wk8   = (unsigned char*)(ws + off);  off += (size_t)DD * 1152;     // 1.125 MB
  unsigned short* wvb   = (unsigned short*)(ws + off); off += (size_t)DD * DD * 2;   // 2 MB
  unsigned short* woutb = (unsigned short*)(ws + off); off += (size_t)DD * DD * 2;   // 2 MB
  float*          kw    = (float*)(ws + off);          off += M * HH * 4;            // 2 MB
  unsigned short* xwb   = (unsigned short*)(ws + off); off += (size_t)HH*BB*GG*DD*2; // 64 MB
  float*          field2= (float*)(ws + off);          off += (size_t)BB*GG*DD*4;    // 8 MB
  unsigned short* fconv2= (unsigned short*)(ws + off); off += (size_t)BB*GG*DD*2;    // 4 MB
  float*          sw    = (float*)(ws + off);          off += (size_t)BB*GG*HH*4;    // 128 KB
  float* small = (float*)xb;   // 8 MB, aliases xb (dead after xw_kernel)

  // 1. bf16 conversions (x, Wv, Wout), then fp8 operands for the k-norm GEMM
  cvt_all<<<8704, 256, 0, stream>>>(x, Wqkv, Wout, xb, wvb, woutb);
  cvt8_kernel<<<(int)M + DD, 256, 0, stream>>>(xb, Wqkv, bqkv, xb8, wk8);

  // 2. kw[n,h] = ||x_n @ Wk_h^T + bk_h||  (MX-fp8 K=128, bias via augmented col)
  gemm_knorm8<<<4 * (M / 256), 512, 0, stream>>>(xb8, wk8, kw, (int)M);

  // 3. xw[h,(b,g),:] = sum_{n in g} w * x[n,:]; sw = sum of weights
  xw_kernel<<<BB * GG, 256, 0, stream>>>(xb, kw, xwb, sw);

  // 4. field2[(b,g), h*64+d] = xw_h @ Wv_h^T + sw*bv
  field_gemm<<<HH * 32, 256, 0, stream>>>(xwb, wvb, sw, bqkv + 2 * DD, field2);

  // 5. circular conv along g -> bf16 (b*512+g, 1024)
  conv_kernel<<<BB * GG, 256, 0, stream>>>(field2, fconv2);

  // 6. small = fconv2 @ Wout^T + bout  (2048 x 1024 f32)
  gemm64<<<(BB * GG / 64) * (DD / 64), 256, 0, stream>>>(
      fconv2, woutb, bout, small, BB * GG, DD, DD);

  // 7. out[b,n,:] = small[(b,g(n)),:]
  expand_kernel<<<4096, 256, 0, stream>>>(small, out);
}

// Round 10
// 457.492 us; speedup vs baseline: 1.3036x; 1.3036x over previous
//
#include <hip/hip_runtime.h>

// Problem constants (B=4, N=8192, D=1024, H=16, hd=64, G=512)
#define BB 4
#define NN 8192
#define DD 1024
#define HH 16
#define HD 64
#define GG 512

typedef short short8 __attribute__((ext_vector_type(8)));
typedef float f32x4 __attribute__((ext_vector_type(4)));
typedef int int4v __attribute__((ext_vector_type(4)));
typedef int int8v __attribute__((ext_vector_type(8)));

__device__ __forceinline__ unsigned short f2bf(float f) {
  union { float f; unsigned int u; } v; v.f = f;
  unsigned int r = v.u + 0x7FFFu + ((v.u >> 16) & 1u);
  return (unsigned short)(r >> 16);
}
__device__ __forceinline__ float bf2f(unsigned short b) {
  union { unsigned int u; float f; } v; v.u = ((unsigned int)b) << 16;
  return v.f;
}

// Async global->LDS 16B copy: LDS dest = wave-uniform base + lane*16 (m104);
// global src is per-lane (m173).
__device__ __forceinline__ void gload16(const void* g, void* l) {
  __builtin_amdgcn_global_load_lds((const __attribute__((address_space(1))) void*)g,
                                   (__attribute__((address_space(3))) void*)l,
                                   16, 0, 0);
}

// Merged f32->bf16 convert: x (8,388,608 float4) then Wv/Wout (262,144 each).
__global__ void cvt_all(const float* __restrict__ x, const float* __restrict__ Wqkv,
                        const float* __restrict__ Wout,
                        unsigned short* __restrict__ xb,
                        unsigned short* __restrict__ wvb, unsigned short* __restrict__ woutb) {
  const int total = 8388608 + 2 * 262144;
  int stride = gridDim.x * blockDim.x;
  for (int j = blockIdx.x * blockDim.x + threadIdx.x; j < total; j += stride) {
    const float4* s; ushort4* d; int r;
    if (j < 8388608) { s = (const float4*)x; d = (ushort4*)xb; r = j; }
    else {
      int q = j - 8388608; int seg = q >> 18; r = q & 262143;
      if (seg == 0) { s = (const float4*)(Wqkv + 2097152); d = (ushort4*)wvb; }
      else          { s = (const float4*)Wout;             d = (ushort4*)woutb; }
    }
    float4 f = s[r];
    ushort4 u;
    u.x = f2bf(f.x); u.y = f2bf(f.y); u.z = f2bf(f.z); u.w = f2bf(f.w);
    d[r] = u;
  }
}

// fp8 operand build, data part (grid-stride, uniform 16B units):
//   xb8 row n bytes 0..1023  = fp8(x_n)          (from bf16 xb)
//   wk8 row d bytes 0..1023  = fp8(32*Wk[d,:])   (from f32 Wqkv)
__global__ void cvt8_data(const unsigned short* __restrict__ xb,
                          const float* __restrict__ Wqkv,
                          unsigned char* __restrict__ xb8,
                          unsigned char* __restrict__ wk8) {
  const int totX = 32768 * 64;            // 16B units in x part
  const int tot = totX + 1024 * 64;
  int stride = gridDim.x * blockDim.x;
  for (int u = blockIdx.x * blockDim.x + threadIdx.x; u < tot; u += stride) {
    unsigned int w[4];
    unsigned char* dst;
    if (u < totX) {
      int r = u >> 6, p = u & 63;
      short8 v = *(const short8*)(xb + (size_t)r * 1024 + p * 16);
      short8 v2 = *(const short8*)(xb + (size_t)r * 1024 + p * 16 + 8);
      #pragma unroll
      for (int q = 0; q < 2; ++q) {
        unsigned int word = 0;
        word = __builtin_amdgcn_cvt_pk_fp8_f32(bf2f((unsigned short)v[q*4+0]),
                                               bf2f((unsigned short)v[q*4+1]), word, false);
        word = __builtin_amdgcn_cvt_pk_fp8_f32(bf2f((unsigned short)v[q*4+2]),
                                               bf2f((unsigned short)v[q*4+3]), word, true);
        w[q] = word;
      }
      #pragma unroll
      for (int q = 0; q < 2; ++q) {
        unsigned int word = 0;
        word = __builtin_amdgcn_cvt_pk_fp8_f32(bf2f((unsigned short)v2[q*4+0]),
                                               bf2f((unsigned short)v2[q*4+1]), word, false);
        word = __builtin_amdgcn_cvt_pk_fp8_f32(bf2f((unsigned short)v2[q*4+2]),
                                               bf2f((unsigned short)v2[q*4+3]), word, true);
        w[2 + q] = word;
      }
      dst = xb8 + (size_t)r * 1152 + p * 16;
    } else {
      int u2 = u - totX;
      int r = u2 >> 6, p = u2 & 63;
      const float* src = Wqkv + 1048576 + (size_t)r * 1024 + p * 16;
      #pragma unroll
      for (int q = 0; q < 4; ++q) {
        unsigned int word = 0;
        word = __builtin_amdgcn_cvt_pk_fp8_f32(src[q*4+0] * 32.0f, src[q*4+1] * 32.0f, word, false);
        word = __builtin_amdgcn_cvt_pk_fp8_f32(src[q*4+2] * 32.0f, src[q*4+3] * 32.0f, word, true);
        w[q] = word;
      }
      dst = wk8 + (size_t)r * 1152 + p * 16;
    }
    uint4 o; o.x = w[0]; o.y = w[1]; o.z = w[2]; o.w = w[3];
    *(uint4*)dst = o;
  }
}

// fp8 operand build, pad part: bytes 1024..1151 of each row.
//   xb8: [fp8(1.0), 0...]; wk8: [fp8(32*bk[d]), 0...]. Augmented col folds bias.
__global__ void cvt8_pad(const float* __restrict__ bqkv,
                         unsigned char* __restrict__ xb8,
                         unsigned char* __restrict__ wk8) {
  int r = blockIdx.x * blockDim.x + threadIdx.x;   // 0..33791
  if (r >= 33792) return;
  unsigned int w0;
  unsigned char* dst;
  if (r < 32768) {
    w0 = __builtin_amdgcn_cvt_pk_fp8_f32(1.0f, 0.0f, 0, false);
    dst = xb8 + (size_t)r * 1152 + 1024;
  } else {
    w0 = __builtin_amdgcn_cvt_pk_fp8_f32(32.0f * bqkv[1024 + r - 32768], 0.0f, 0, false);
    dst = wk8 + (size_t)(r - 32768) * 1152 + 1024;
  }
  uint4 z0; z0.x = w0; z0.y = 0; z0.z = 0; z0.w = 0;
  uint4 z;  z.x = 0;  z.y = 0;  z.z = 0;  z.w = 0;
  *(uint4*)dst = z0;
  #pragma unroll
  for (int p = 1; p < 8; ++p) *(uint4*)(dst + p * 16) = z;
}

// ========== MX-fp8 k-norm GEMM (m148 geometry): kw[n,h] = ||k_n_h + bk_h|| ====
// 128x128 tile, 4 waves (2x2), per-wave 64x64 out (acc[4][4], 64 VGPR — no
// spill; R9's 256^2 spilled acc to scratch). BK=128 fp8 bytes, K=1152 (9 tiles),
// single 32 KB LDS buffer, m97 2-barrier loop (occupancy-driven overlap).
// slot^(row&7) involution swizzle on both sides. acc = 32*(k+b) via augmented
// column; epilogue sqrt(sum (acc/32)^2) — layout-proof (norm over the head).
__global__ __launch_bounds__(256, 2) void gemm_knorm8(
    const unsigned char* __restrict__ A,   // xb8: M x 1152
    const unsigned char* __restrict__ Bm,  // wk8: 1024 x 1152
    float* __restrict__ Cout, int M) {
  __shared__ __align__(16) unsigned char As[16384];  // 128 rows x 128 B
  __shared__ __align__(16) unsigned char Bs[16384];

  const int t256 = threadIdx.x;
  const int wv = t256 >> 6, lane = t256 & 63;
  const int wm = wv >> 1, wn = wv & 1;
  const int l15 = lane & 15, sr = lane >> 4;

  // XCD-aware bijective swizzle (grid = 2048, %8==0)
  const int nwg = gridDim.x;
  const int lin = blockIdx.x;
  const int swz = (lin & 7) * (nwg >> 3) + (lin >> 3);
  const int bm = (swz >> 3) * 128;          // 256 m-blocks
  const int bn = (swz & 7) * 128;           // 8 n-blocks

  // staging: pass p covers rows p*32 + wv*8 .. +8; lane -> row lane>>3, phys
  // slot lane&7. Phys slot ps of row r holds global slot ps^(r&7) (involution).
  auto stage = [&](int t) {
    #pragma unroll
    for (int p = 0; p < 4; ++p) {
      int ra = p * 32 + wv * 8 + (lane >> 3);
      int gs = (lane & 7) ^ (ra & 7);
      gload16(A + (size_t)(bm + ra) * 1152 + t * 128 + gs * 16, &As[(p * 32 + wv * 8) * 128]);
      gload16(Bm + (size_t)(bn + ra) * 1152 + t * 128 + gs * 16, &Bs[(p * 32 + wv * 8) * 128]);
    }
  };

  // fragment LDS byte offsets (swizzled): lane frag = 32 B = 2 x 16B slots
  int aOff[4][2], bOff[4][2];
  #pragma unroll
  for (int i = 0; i < 4; ++i) {
    int r = wm * 64 + i * 16 + l15;
    #pragma unroll
    for (int h = 0; h < 2; ++h)
      aOff[i][h] = r * 128 + (((sr * 2 + h) ^ (r & 7)) * 16);
  }
  #pragma unroll
  for (int j = 0; j < 4; ++j) {
    int r = wn * 64 + j * 16 + l15;
    #pragma unroll
    for (int h = 0; h < 2; ++h)
      bOff[j][h] = r * 128 + (((sr * 2 + h) ^ (r & 7)) * 16);
  }

  union U8 { int4v h[2]; int8v v; };
  f32x4 acc[4][4] = {};

  for (int t = 0; t < 9; ++t) {
    stage(t);
    __syncthreads();                      // drains vmcnt: tile t resident
    U8 b8[4];
    #pragma unroll
    for (int j = 0; j < 4; ++j) {
      b8[j].h[0] = *(const int4v*)(Bs + bOff[j][0]);
      b8[j].h[1] = *(const int4v*)(Bs + bOff[j][1]);
    }
    #pragma unroll
    for (int i = 0; i < 4; ++i) {
      U8 a8;
      a8.h[0] = *(const int4v*)(As + aOff[i][0]);
      a8.h[1] = *(const int4v*)(As + aOff[i][1]);
      #pragma unroll
      for (int j = 0; j < 4; ++j)
        acc[i][j] = __builtin_amdgcn_mfma_scale_f32_16x16x128_f8f6f4(
            a8.v, b8[j].v, acc[i][j], 0, 0, 0, 127, 0, 127);  // fp8/fp8, scale=1
    }
    __syncthreads();                      // LDS reads done before next stage
  }

  // Epilogue: norm over this wave's head (cols bn+wn*64..+64). C/D layout
  // col=l15, row=sr*4+reg per 16x16 frag (R9-validated end-to-end).
  const int hcol = (bn >> 6) + wn;
  #pragma unroll
  for (int i = 0; i < 4; ++i) {
    #pragma unroll
    for (int r = 0; r < 4; ++r) {
      float s = 0.0f;
      #pragma unroll
      for (int j = 0; j < 4; ++j) {
        float val = acc[i][j][r] * 0.03125f;   // undo x32 weight pre-scale
        s += val * val;
      }
      s += __shfl_xor(s, 1, 64);
      s += __shfl_xor(s, 2, 64);
      s += __shfl_xor(s, 4, 64);
      s += __shfl_xor(s, 8, 64);
      if (l15 == 0) {
        int row = bm + wm * 64 + i * 16 + sr * 4 + r;
        Cout[(size_t)row * 16 + hcol] = sqrtf(s);
      }
    }
  }
}

// xw: per (b,g) bucket, xw[h,:] = sum_{n in g} w[n,h] * x[n,:]; sw[h] = sum w.
__global__ __launch_bounds__(256) void xw_kernel(
    const unsigned short* __restrict__ xb, const float* __restrict__ kw,
    unsigned short* __restrict__ xwb, float* __restrict__ sw) {
  __shared__ float w_l[20][16];
  __shared__ int mflag[20];
  const int bg = blockIdx.x;             // b*512+g
  const int b = bg >> 9, g = bg & 511;
  const int t = threadIdx.x;
  int lo = (g * (NN - 1)) / (GG - 1) - 2;
  if (lo < 0) lo = 0;
  if (t < 20) {
    int n = lo + t;
    // EXACT ref bucket math: trunc((n/8191)*511)
    mflag[t] = (n < NN) && ((int)(((float)n / 8191.0f) * 511.0f) == g);
  }
  for (int u = t; u < 320; u += 256) {
    int ln = u >> 4, h = u & 15;
    int n = lo + ln;
    float w = 0.0f;
    if (n < NN && (int)(((float)n / 8191.0f) * 511.0f) == g)
      w = kw[((size_t)(b * NN + n)) * 16 + h];
    w_l[ln][h] = w;
  }
  __syncthreads();
  if (t < 16) {
    float s = 0.0f;
    #pragma unroll
    for (int ln = 0; ln < 20; ++ln) s += w_l[ln][t];
    sw[bg * 16 + t] = s;
  }
  float acc[16][4] = {};
  const int c0 = t * 4;
  for (int ln = 0; ln < 20; ++ln) {
    if (!mflag[ln]) continue;            // wave-uniform branch
    int n = lo + ln;
    ushort4 xv = *(const ushort4*)(xb + ((size_t)(b * NN + n)) * 1024 + c0);
    float x0 = bf2f(xv.x), x1 = bf2f(xv.y), x2 = bf2f(xv.z), x3 = bf2f(xv.w);
    #pragma unroll
    for (int h = 0; h < 16; ++h) {
      float w = w_l[ln][h];
      acc[h][0] += w * x0; acc[h][1] += w * x1;
      acc[h][2] += w * x2; acc[h][3] += w * x3;
    }
  }
  #pragma unroll
  for (int h = 0; h < 16; ++h) {
    ushort4 o;
    o.x = f2bf(acc[h][0]); o.y = f2bf(acc[h][1]);
    o.z = f2bf(acc[h][2]); o.w = f2bf(acc[h][3]);
    *(ushort4*)(xwb + ((size_t)h * 2048 + bg) * 1024 + c0) = o;
  }
}

// field GEMM: per h, field2[(b,g), h*64+d] = xw_h[(b,g),:] . Wv[h*64+d,:] + sw*bv.
__global__ __launch_bounds__(256, 2) void field_gemm(
    const unsigned short* __restrict__ xwb, const unsigned short* __restrict__ wvb,
    const float* __restrict__ sw, const float* __restrict__ bv,
    float* __restrict__ field2) {
  __shared__ __align__(16) unsigned short As[2][64 * 32];  // 4 KB x2
  __shared__ __align__(16) unsigned short Bs[2][64 * 32];  // 4 KB x2
  const int h = blockIdx.x >> 5;           // 16 h
  const int mb = blockIdx.x & 31;          // 32 m-blocks of 64
  const int t = threadIdx.x;
  const int wv_ = t >> 6, lane = t & 63;
  const int l15 = lane & 15, sr = lane >> 4;

  const unsigned short* Ah = xwb + (size_t)h * 2048 * 1024 + (size_t)mb * 64 * 1024;
  const unsigned short* Bh = wvb + (size_t)h * 64 * 1024;

  const int srow = wv_ * 16 + (lane >> 2);          // 0..63
  const int sg = (lane & 3) ^ ((srow >> 1) & 3);    // swizzled k-segment
  const int dL = wv_ * 1024;                        // wave-uniform LDS bytes

  const unsigned short* aG = Ah + (size_t)srow * 1024 + sg * 8;
  const unsigned short* bG = Bh + (size_t)srow * 1024 + sg * 8;

  auto stage = [&](int tt, int q) {
    gload16(aG + tt * 32, (char*)As[q] + dL);
    gload16(bG + tt * 32, (char*)Bs[q] + dL);
  };

  int aOff, bOff[4];
  {
    int r = wv_ * 16 + l15;
    aOff = r * 64 + ((sr ^ ((r >> 1) & 3)) * 16);
  }
  #pragma unroll
  for (int j = 0; j < 4; ++j) {
    int r = j * 16 + l15;
    bOff[j] = r * 64 + ((sr ^ ((r >> 1) & 3)) * 16);
  }

  f32x4 acc[4] = {};
  stage(0, 0);
  for (int tt = 0; tt < 32; ++tt) {
    if (tt + 1 < 32) {
      stage(tt + 1, (tt + 1) & 1);
      asm volatile("s_waitcnt vmcnt(2)" ::: "memory");  // tile tt landed
    } else {
      asm volatile("s_waitcnt vmcnt(0)" ::: "memory");
    }
    __builtin_amdgcn_s_barrier();
    const char* a = (const char*)As[tt & 1];
    const char* bb = (const char*)Bs[tt & 1];
    short8 aF = *(const short8*)(a + aOff);
    short8 bF[4];
    #pragma unroll
    for (int j = 0; j < 4; ++j) bF[j] = *(const short8*)(bb + bOff[j]);
    #pragma unroll
    for (int j = 0; j < 4; ++j)
      acc[j] = __builtin_amdgcn_mfma_f32_16x16x32_bf16(aF, bF[j], acc[j], 0, 0, 0);
    __builtin_amdgcn_s_barrier();
  }

  const int row0 = mb * 64 + wv_ * 16 + sr * 4;
  #pragma unroll
  for (int r = 0; r < 4; ++r) {
    float swv = sw[(row0 + r) * 16 + h];
    #pragma unroll
    for (int j = 0; j < 4; ++j) {
      int col = h * 64 + j * 16 + l15;
      field2[(size_t)(row0 + r) * 1024 + col] = acc[j][r] + swv * bv[col];
    }
  }
}

// Small out-projection GEMM: 64x64 tile, 512 blocks (full CU coverage).
__global__ __launch_bounds__(256, 4) void gemm64(
    const unsigned short* __restrict__ A, const unsigned short* __restrict__ Bm,
    const float* __restrict__ bias, float* __restrict__ C,
    int M, int N, int K) {
  __shared__ __align__(16) unsigned short As[2][64 * 32];
  __shared__ __align__(16) unsigned short Bs[2][64 * 32];
  const int nb = N >> 6;
  const int mb = blockIdx.x / nb, nk = blockIdx.x % nb;
  const int t = threadIdx.x;
  const int wv_ = t >> 6, lane = t & 63;
  const int l15 = lane & 15, sr = lane >> 4;
  const int nt = K >> 5;

  const unsigned short* Ab = A + (size_t)mb * 64 * K;
  const unsigned short* Bb = Bm + (size_t)nk * 64 * K;

  const int srow = wv_ * 16 + (lane >> 2);
  const int sg = (lane & 3) ^ ((srow >> 1) & 3);
  const int dL = wv_ * 1024;

  const unsigned short* aG = Ab + (size_t)srow * K + sg * 8;
  const unsigned short* bG = Bb + (size_t)srow * K + sg * 8;

  auto stage = [&](int tt, int q) {
    gload16(aG + tt * 32, (char*)As[q] + dL);
    gload16(bG + tt * 32, (char*)Bs[q] + dL);
  };

  int aOff, bOff[4];
  {
    int r = wv_ * 16 + l15;
    aOff = r * 64 + ((sr ^ ((r >> 1) & 3)) * 16);
  }
  #pragma unroll
  for (int j = 0; j < 4; ++j) {
    int r = j * 16 + l15;
    bOff[j] = r * 64 + ((sr ^ ((r >> 1) & 3)) * 16);
  }

  f32x4 acc[4] = {};
  stage(0, 0);
  for (int tt = 0; tt < nt; ++tt) {
    if (tt + 1 < nt) {
      stage(tt + 1, (tt + 1) & 1);
      asm volatile("s_waitcnt vmcnt(2)" ::: "memory");
    } else {
      asm volatile("s_waitcnt vmcnt(0)" ::: "memory");
    }
    __builtin_amdgcn_s_barrier();
    const char* a = (const char*)As[tt & 1];
    const char* bb = (const char*)Bs[tt & 1];
    short8 aF = *(const short8*)(a + aOff);
    short8 bF[4];
    #pragma unroll
    for (int j = 0; j < 4; ++j) bF[j] = *(const short8*)(bb + bOff[j]);
    #pragma unroll
    for (int j = 0; j < 4; ++j)
      acc[j] = __builtin_amdgcn_mfma_f32_16x16x32_bf16(aF, bF[j], acc[j], 0, 0, 0);
    __builtin_amdgcn_s_barrier();
  }

  const int row0 = mb * 64 + wv_ * 16 + sr * 4;
  #pragma unroll
  for (int r = 0; r < 4; ++r) {
    #pragma unroll
    for (int j = 0; j < 4; ++j) {
      int col = nk * 64 + j * 16 + l15;
      C[(size_t)(row0 + r) * N + col] = acc[j][r] + bias[col];
    }
  }
}

// Circular conv along g: out[g] = sum_m w_m in[(g+256+m)&511], w iterative.
__global__ void conv_kernel(const float* __restrict__ field2,
                            unsigned short* __restrict__ fconv2) {
  int i = blockIdx.x * blockDim.x + threadIdx.x;   // 2048*256 float4 units
  int c4 = i & 255;
  int bg = i >> 8;
  int b = bg >> 9, g = bg & 511;
  const float4* f4 = (const float4*)field2;
  float w = 0.86466471f;                           // invZ
  const float dec = 0.13533528f;                   // e^{-2}
  float4 s = {0.f, 0.f, 0.f, 0.f};
  #pragma unroll
  for (int m = 0; m <= 20; ++m) {
    float4 v = f4[(size_t)((b << 9) + ((g + 256 + m) & 511)) * 256 + c4];
    s.x += w * v.x; s.y += w * v.y; s.z += w * v.z; s.w += w * v.w;
    w *= dec;
  }
  ushort4 o;
  o.x = f2bf(s.x); o.y = f2bf(s.y); o.z = f2bf(s.z); o.w = f2bf(s.w);
  *(ushort4*)(fconv2 + (size_t)bg * 1024 + c4 * 4) = o;
}

// Row-expand: out[b,n,:] = small[(b,g(n)),:]
__global__ void expand_kernel(const float* __restrict__ small,
                              float* __restrict__ out) {
  const int total = 32768 * 256;
  int stride = gridDim.x * blockDim.x;
  for (int i = blockIdx.x * blockDim.x + threadIdx.x; i < total; i += stride) {
    int m = i >> 8;
    int b = m >> 13, n = m & (NN - 1);
    int g = (int)(((float)n / 8191.0f) * 511.0f); // exact ref index math
    ((float4*)out)[i] = ((const float4*)small)[(((b << 9) + g) << 8) + (i & 255)];
  }
}

extern "C" void kernel_launch(void* const* d_in, const int* in_sizes, int n_in,
                              void* d_out, int out_size, void* d_ws, size_t ws_size,
                              hipStream_t stream) {
  const float* x    = (const float*)d_in[0];   // (4,8192,1024)
  const float* Wqkv = (const float*)d_in[1];   // (3072,1024)
  const float* bqkv = (const float*)d_in[2];   // (3072,)
  const float* Wout = (const float*)d_in[3];   // (1024,1024)
  const float* bout = (const float*)d_in[4];   // (1024,)
  float* out = (float*)d_out;                  // (4,8192,1024) f32

  const size_t M = (size_t)BB * NN;            // 32768

  // Workspace layout
  char* ws = (char*)d_ws;
  size_t off = 0;
  unsigned short* xb    = (unsigned short*)(ws + off); off += M * DD * 2;            // 64 MB
  unsigned char*  xb8   = (unsigned char*)(ws + off);  off += M * 1152;              // 37.75 MB
  unsigned char*  wk8   = (unsigned char*)(ws + off);  off += (size_t)DD * 1152;     // 1.125 MB
  unsigned short* wvb   = (unsigned short*)(ws + off); off += (size_t)DD * DD * 2;   // 2 MB
  unsigned short* woutb = (unsigned short*)(ws + off); off += (size_t)DD * DD * 2;   // 2 MB
  float*          kw    = (float*)(ws + off);          off += M * HH * 4;            // 2 MB
  unsigned short* xwb   = (unsigned short*)(ws + off); off += (size_t)HH*BB*GG*DD*2; // 64 MB
  float*          field2= (float*)(ws + off);          off += (size_t)BB*GG*DD*4;    // 8 MB
  unsigned short* fconv2= (unsigned short*)(ws + off); off += (size_t)BB*GG*DD*2;    // 4 MB
  float*          sw    = (float*)(ws + off);          off += (size_t)BB*GG*HH*4;    // 128 KB
  float* small = (float*)xb;   // 8 MB, aliases xb (dead after xw_kernel)

  // 1. bf16 conversions (x, Wv, Wout), then fp8 operands for the k-norm GEMM
  cvt_all<<<8704, 256, 0, stream>>>(x, Wqkv, Wout, xb, wvb, woutb);
  cvt8_data<<<2048, 256, 0, stream>>>(xb, Wqkv, xb8, wk8);
  cvt8_pad<<<132, 256, 0, stream>>>(bqkv, xb8, wk8);

  // 2. kw[n,h] = ||x_n @ Wk_h^T + bk_h||  (MX-fp8 K=128, 128^2 tile, m148 geom)
  gemm_knorm8<<<8 * (M / 128), 256, 0, stream>>>(xb8, wk8, kw, (int)M);

  // 3. xw[h,(b,g),:] = sum_{n in g} w * x[n,:]; sw = sum of weights
  xw_kernel<<<BB * GG, 256, 0, stream>>>(xb, kw, xwb, sw);

  // 4. field2[(b,g), h*64+d] = xw_h @ Wv_h^T + sw*bv
  field_gemm<<<HH * 32, 256, 0, stream>>>(xwb, wvb, sw, bqkv + 2 * DD, field2);

  // 5. circular conv along g -> bf16 (b*512+g, 1024)
  conv_kernel<<<BB * GG, 256, 0, stream>>>(field2, fconv2);

  // 6. small = fconv2 @ Wout^T + bout  (2048 x 1024 f32)
  gemm64<<<(BB * GG / 64) * (DD / 64), 256, 0, stream>>>(
      fconv2, woutb, bout, small, BB * GG, DD, DD);

  // 7. out[b,n,:] = small[(b,g(n)),:]
  expand_kernel<<<4096, 256, 0, stream>>>(small, out);
}

// Round 11
// 229.118 us; speedup vs baseline: 2.6029x; 1.9968x over previous
//
#include <hip/hip_runtime.h>

// Problem constants (B=4, N=8192, D=1024, H=16, hd=64, G=512)
#define BB 4
#define NN 8192
#define DD 1024
#define HH 16
#define HD 64
#define GG 512

typedef short short8 __attribute__((ext_vector_type(8)));
typedef float f32x4 __attribute__((ext_vector_type(4)));

__device__ __forceinline__ unsigned short f2bf(float f) {
  union { float f; unsigned int u; } v; v.f = f;
  unsigned int r = v.u + 0x7FFFu + ((v.u >> 16) & 1u);
  return (unsigned short)(r >> 16);
}
__device__ __forceinline__ float bf2f(unsigned short b) {
  union { unsigned int u; float f; } v; v.u = ((unsigned int)b) << 16;
  return v.f;
}

// Async global->LDS 16B copy: LDS dest = wave-uniform base + lane*16 (m104);
// global src is per-lane (m173).
__device__ __forceinline__ void gload16(const void* g, void* l) {
  __builtin_amdgcn_global_load_lds((const __attribute__((address_space(1))) void*)g,
                                   (__attribute__((address_space(3))) void*)l,
                                   16, 0, 0);
}

// Merged f32->bf16 convert: x (8,388,608 float4) then Wk/Wv/Wout (262,144 each).
__global__ void cvt_all(const float* __restrict__ x, const float* __restrict__ Wqkv,
                        const float* __restrict__ Wout,
                        unsigned short* __restrict__ xb, unsigned short* __restrict__ wkb,
                        unsigned short* __restrict__ wvb, unsigned short* __restrict__ woutb) {
  const int total = 8388608 + 3 * 262144;
  int stride = gridDim.x * blockDim.x;
  for (int j = blockIdx.x * blockDim.x + threadIdx.x; j < total; j += stride) {
    const float4* s; ushort4* d; int r;
    if (j < 8388608) { s = (const float4*)x; d = (ushort4*)xb; r = j; }
    else {
      int q = j - 8388608; int seg = q >> 18; r = q & 262143;
      if (seg == 0)      { s = (const float4*)(Wqkv + 1048576); d = (ushort4*)wkb; }
      else if (seg == 1) { s = (const float4*)(Wqkv + 2097152); d = (ushort4*)wvb; }
      else               { s = (const float4*)Wout;             d = (ushort4*)woutb; }
    }
    float4 f = s[r];
    ushort4 u;
    u.x = f2bf(f.x); u.y = f2bf(f.y); u.z = f2bf(f.z); u.w = f2bf(f.w);
    d[r] = u;
  }
}

// xw: per (b,g) bucket, xw[h,:] = sum_{n in g} w[n,h] * x[n,:]; sw[h] = sum w.
// kw already holds w = ||k|| (sqrt fused into gemm_knorm epilogue).
// Window of 20 n covers any bucket (width ~16.03); membership-flagged rows only
// (skipping non-members is bit-identical: their w was exactly 0).
__global__ __launch_bounds__(256) void xw_kernel(
    const unsigned short* __restrict__ xb, const float* __restrict__ kw,
    unsigned short* __restrict__ xwb, float* __restrict__ sw) {
  __shared__ float w_l[20][16];
  __shared__ int mflag[20];
  const int bg = blockIdx.x;             // b*512+g
  const int b = bg >> 9, g = bg & 511;
  const int t = threadIdx.x;
  int lo = (g * (NN - 1)) / (GG - 1) - 2;
  if (lo < 0) lo = 0;
  if (t < 20) {
    int n = lo + t;
    // EXACT ref bucket math: trunc((n/8191)*511)
    mflag[t] = (n < NN) && ((int)(((float)n / 8191.0f) * 511.0f) == g);
  }
  for (int u = t; u < 320; u += 256) {
    int ln = u >> 4, h = u & 15;
    int n = lo + ln;
    float w = 0.0f;
    if (n < NN && (int)(((float)n / 8191.0f) * 511.0f) == g)
      w = kw[((size_t)(b * NN + n)) * 16 + h];
    w_l[ln][h] = w;
  }
  __syncthreads();
  if (t < 16) {
    float s = 0.0f;
    #pragma unroll
    for (int ln = 0; ln < 20; ++ln) s += w_l[ln][t];
    sw[bg * 16 + t] = s;
  }
  float acc[16][4] = {};
  const int c0 = t * 4;
  for (int ln = 0; ln < 20; ++ln) {
    if (!mflag[ln]) continue;            // wave-uniform branch
    int n = lo + ln;
    ushort4 xv = *(const ushort4*)(xb + ((size_t)(b * NN + n)) * 1024 + c0);
    float x0 = bf2f(xv.x), x1 = bf2f(xv.y), x2 = bf2f(xv.z), x3 = bf2f(xv.w);
    #pragma unroll
    for (int h = 0; h < 16; ++h) {
      float w = w_l[ln][h];
      acc[h][0] += w * x0; acc[h][1] += w * x1;
      acc[h][2] += w * x2; acc[h][3] += w * x3;
    }
  }
  #pragma unroll
  for (int h = 0; h < 16; ++h) {
    ushort4 o;
    o.x = f2bf(acc[h][0]); o.y = f2bf(acc[h][1]);
    o.z = f2bf(acc[h][2]); o.w = f2bf(acc[h][3]);
    *(ushort4*)(xwb + ((size_t)h * 2048 + bg) * 1024 + c0) = o;
  }
}

// field GEMM: per h, field2[(b,g), h*64+d] = xw_h[(b,g),:] . Wv[h*64+d,:] + sw*bv.
// M-tile 64, N=64 (one head), K=1024. 4 waves, 2-deep ring, counted vmcnt.
__global__ __launch_bounds__(256, 2) void field_gemm(
    const unsigned short* __restrict__ xwb, const unsigned short* __restrict__ wvb,
    const float* __restrict__ sw, const float* __restrict__ bv,
    float* __restrict__ field2) {
  __shared__ __align__(16) unsigned short As[2][64 * 32];  // 4 KB x2
  __shared__ __align__(16) unsigned short Bs[2][64 * 32];  // 4 KB x2
  const int h = blockIdx.x >> 5;           // 16 h
  const int mb = blockIdx.x & 31;          // 32 m-blocks of 64
  const int t = threadIdx.x;
  const int wv_ = t >> 6, lane = t & 63;
  const int l15 = lane & 15, sr = lane >> 4;

  const unsigned short* Ah = xwb + (size_t)h * 2048 * 1024 + (size_t)mb * 64 * 1024;
  const unsigned short* Bh = wvb + (size_t)h * 64 * 1024;

  const int srow = wv_ * 16 + (lane >> 2);          // 0..63
  const int sg = (lane & 3) ^ ((srow >> 1) & 3);    // swizzled k-segment
  const int dL = wv_ * 1024;                        // wave-uniform LDS bytes

  const unsigned short* aG = Ah + (size_t)srow * 1024 + sg * 8;
  const unsigned short* bG = Bh + (size_t)srow * 1024 + sg * 8;

  auto stage = [&](int tt, int q) {
    gload16(aG + tt * 32, (char*)As[q] + dL);
    gload16(bG + tt * 32, (char*)Bs[q] + dL);
  };

  int aOff, bOff[4];
  {
    int r = wv_ * 16 + l15;
    aOff = r * 64 + ((sr ^ ((r >> 1) & 3)) * 16);
  }
  #pragma unroll
  for (int j = 0; j < 4; ++j) {
    int r = j * 16 + l15;
    bOff[j] = r * 64 + ((sr ^ ((r >> 1) & 3)) * 16);
  }

  f32x4 acc[4] = {};
  stage(0, 0);
  for (int tt = 0; tt < 32; ++tt) {
    if (tt + 1 < 32) {
      stage(tt + 1, (tt + 1) & 1);
      asm volatile("s_waitcnt vmcnt(2)" ::: "memory");  // tile tt landed
    } else {
      asm volatile("s_waitcnt vmcnt(0)" ::: "memory");
    }
    __builtin_amdgcn_s_barrier();
    const char* a = (const char*)As[tt & 1];
    const char* bb = (const char*)Bs[tt & 1];
    short8 aF = *(const short8*)(a + aOff);
    short8 bF[4];
    #pragma unroll
    for (int j = 0; j < 4; ++j) bF[j] = *(const short8*)(bb + bOff[j]);
    #pragma unroll
    for (int j = 0; j < 4; ++j)
      acc[j] = __builtin_amdgcn_mfma_f32_16x16x32_bf16(aF, bF[j], acc[j], 0, 0, 0);
    __builtin_amdgcn_s_barrier();
  }

  const int row0 = mb * 64 + wv_ * 16 + sr * 4;
  #pragma unroll
  for (int r = 0; r < 4; ++r) {
    float swv = sw[(row0 + r) * 16 + h];
    #pragma unroll
    for (int j = 0; j < 4; ++j) {
      int col = h * 64 + j * 16 + l15;
      field2[(size_t)(row0 + r) * 1024 + col] = acc[j][r] + swv * bv[col];
    }
  }
}

// Small GEMM for the out-projection: C[m][n] = sum_k A[m][k]*B[n][k] + bias[n].
// 64x64 tile, 4 waves, 2-deep ring -> 512 blocks (full CU coverage).
__global__ __launch_bounds__(256, 4) void gemm64(
    const unsigned short* __restrict__ A, const unsigned short* __restrict__ Bm,
    const float* __restrict__ bias, float* __restrict__ C,
    int M, int N, int K) {
  __shared__ __align__(16) unsigned short As[2][64 * 32];  // 4 KB x2
  __shared__ __align__(16) unsigned short Bs[2][64 * 32];
  const int nb = N >> 6;
  const int mb = blockIdx.x / nb, nk = blockIdx.x % nb;
  const int t = threadIdx.x;
  const int wv_ = t >> 6, lane = t & 63;
  const int l15 = lane & 15, sr = lane >> 4;
  const int nt = K >> 5;

  const unsigned short* Ab = A + (size_t)mb * 64 * K;
  const unsigned short* Bb = Bm + (size_t)nk * 64 * K;

  const int srow = wv_ * 16 + (lane >> 2);
  const int sg = (lane & 3) ^ ((srow >> 1) & 3);
  const int dL = wv_ * 1024;

  const unsigned short* aG = Ab + (size_t)srow * K + sg * 8;
  const unsigned short* bG = Bb + (size_t)srow * K + sg * 8;

  auto stage = [&](int tt, int q) {
    gload16(aG + tt * 32, (char*)As[q] + dL);
    gload16(bG + tt * 32, (char*)Bs[q] + dL);
  };

  int aOff, bOff[4];
  {
    int r = wv_ * 16 + l15;
    aOff = r * 64 + ((sr ^ ((r >> 1) & 3)) * 16);
  }
  #pragma unroll
  for (int j = 0; j < 4; ++j) {
    int r = j * 16 + l15;
    bOff[j] = r * 64 + ((sr ^ ((r >> 1) & 3)) * 16);
  }

  f32x4 acc[4] = {};
  stage(0, 0);
  for (int tt = 0; tt < nt; ++tt) {
    if (tt + 1 < nt) {
      stage(tt + 1, (tt + 1) & 1);
      asm volatile("s_waitcnt vmcnt(2)" ::: "memory");  // tile tt landed
    } else {
      asm volatile("s_waitcnt vmcnt(0)" ::: "memory");
    }
    __builtin_amdgcn_s_barrier();
    const char* a = (const char*)As[tt & 1];
    const char* bb = (const char*)Bs[tt & 1];
    short8 aF = *(const short8*)(a + aOff);
    short8 bF[4];
    #pragma unroll
    for (int j = 0; j < 4; ++j) bF[j] = *(const short8*)(bb + bOff[j]);
    #pragma unroll
    for (int j = 0; j < 4; ++j)
      acc[j] = __builtin_amdgcn_mfma_f32_16x16x32_bf16(aF, bF[j], acc[j], 0, 0, 0);
    __builtin_amdgcn_s_barrier();
  }

  const int row0 = mb * 64 + wv_ * 16 + sr * 4;
  #pragma unroll
  for (int r = 0; r < 4; ++r) {
    #pragma unroll
    for (int j = 0; j < 4; ++j) {
      int col = nk * 64 + j * 16 + l15;
      C[(size_t)(row0 + r) * N + col] = acc[j][r] + bias[col];
    }
  }
}

// Circular conv along g on (b*512+g, 1024) layout: out[g] = sum_m w_m in[(g+256+m)&511],
// w_m = invZ * e^{-2m} computed iteratively (no expf).
__global__ void conv_kernel(const float* __restrict__ field2,
                            unsigned short* __restrict__ fconv2) {
  int i = blockIdx.x * blockDim.x + threadIdx.x;   // 2048*256 float4 units
  int c4 = i & 255;
  int bg = i >> 8;
  int b = bg >> 9, g = bg & 511;
  const float4* f4 = (const float4*)field2;
  float w = 0.86466471f;                           // invZ = 1/(sum e^{-2m} + 1e-8)
  const float dec = 0.13533528f;                   // e^{-2}
  float4 s = {0.f, 0.f, 0.f, 0.f};
  #pragma unroll
  for (int m = 0; m <= 20; ++m) {
    float4 v = f4[(size_t)((b << 9) + ((g + 256 + m) & 511)) * 256 + c4];
    s.x += w * v.x; s.y += w * v.y; s.z += w * v.z; s.w += w * v.w;
    w *= dec;
  }
  ushort4 o;
  o.x = f2bf(s.x); o.y = f2bf(s.y); o.z = f2bf(s.z); o.w = f2bf(s.w);
  *(ushort4*)(fconv2 + (size_t)bg * 1024 + c4 * 4) = o;
}

// Row-expand: out[b,n,:] = small[(b,g(n)),:]  (bias already in small).
__global__ void expand_kernel(const float* __restrict__ small,
                              float* __restrict__ out) {
  const int total = 32768 * 256;                  // rows x (1024/4) float4
  int stride = gridDim.x * blockDim.x;
  for (int i = blockIdx.x * blockDim.x + threadIdx.x; i < total; i += stride) {
    int m = i >> 8;
    int b = m >> 13, n = m & (NN - 1);
    int g = (int)(((float)n / 8191.0f) * 511.0f); // exact ref index math
    ((float4*)out)[i] = ((const float4*)small)[(((b << 9) + g) << 8) + (i & 255)];
  }
}

// ============ 256x256 ring-pipelined MFMA GEMM (k-norm epilogue) ============
// kw[row,h] = ||x_row @ Wk_h^T + bk_h|| via fused epilogue (sqrt included);
// each wave's 64-col span is one head. 2-phase interleave, ring-4 LDS,
// counted vmcnt, XOR-swizzle (0 bank conflicts, verified R3).
__global__ __launch_bounds__(512, 2) void gemm_knorm(
    const unsigned short* __restrict__ A, const unsigned short* __restrict__ Bm,
    const float* __restrict__ bias, float* __restrict__ Cout,
    int M, int N, int K) {
  __shared__ __align__(16) unsigned short smem[4 * 16384];  // 128 KB

  const int t512 = threadIdx.x;
  const int wv = t512 >> 6, lane = t512 & 63;
  const int wm = wv >> 2, wn = wv & 3;
  const int l15 = lane & 15, sr = lane >> 4;
  const int nt = K >> 5;

  // XCD-aware bijective block swizzle (grid divisible by 8)
  const int nwg = gridDim.x;
  const int lin = blockIdx.x;
  const int swz = (lin & 7) * (nwg >> 3) + (lin >> 3);
  const int gx = N >> 8;
  const int bm = (swz / gx) * 256;
  const int bn = (swz % gx) * 256;

  const int srow0 = wv * 16 + (lane >> 2);
  const int sg = (lane & 3) ^ ((srow0 >> 1) & 3);
  const int aL0 = wv * 1024;
  const int aL1 = 8192 + wv * 1024;

  const unsigned short* aG0 = A + (size_t)(bm + srow0) * K + sg * 8;
  const unsigned short* aG1 = A + (size_t)(bm + srow0 + 128) * K + sg * 8;
  const unsigned short* bG0 = Bm + (size_t)(bn + srow0) * K + sg * 8;
  const unsigned short* bG1 = Bm + (size_t)(bn + srow0 + 128) * K + sg * 8;

  auto stageA = [&](int t, int q) {
    char* base = (char*)smem + q * 32768;
    gload16(aG0 + (size_t)t * 32, base + aL0);
    gload16(aG1 + (size_t)t * 32, base + aL1);
  };
  auto stageB = [&](int t, int q) {
    char* base = (char*)smem + q * 32768;
    gload16(bG0 + (size_t)t * 32, base + 16384 + aL0);
    gload16(bG1 + (size_t)t * 32, base + 16384 + aL1);
  };

  int aOffB[8], bOffB[4];
  #pragma unroll
  for (int i = 0; i < 8; ++i) {
    int r = wm * 128 + i * 16 + l15;
    aOffB[i] = r * 64 + ((sr ^ ((r >> 1) & 3)) * 16);
  }
  #pragma unroll
  for (int j = 0; j < 4; ++j) {
    int r = wn * 64 + j * 16 + l15;
    bOffB[j] = r * 64 + ((sr ^ ((r >> 1) & 3)) * 16);
  }

  f32x4 acc[8][4] = {};

  stageA(0, 0); stageB(0, 0);
  stageA(1, 1); stageB(1, 1);
  stageA(2, 2); stageB(2, 2);
  asm volatile("s_waitcnt vmcnt(8)" ::: "memory");
  __builtin_amdgcn_s_barrier();

  for (int t = 0; t < nt; ++t) {
    const char* base = (const char*)smem + (t & 3) * 32768;
    short8 aF[8], bF[4];

    if (t + 3 < nt) stageA(t + 3, (t + 3) & 3);
    #pragma unroll
    for (int i = 0; i < 4; ++i) aF[i] = *(const short8*)(base + aOffB[i]);
    #pragma unroll
    for (int j = 0; j < 4; ++j) bF[j] = *(const short8*)(base + 16384 + bOffB[j]);
    __builtin_amdgcn_s_barrier();
    __builtin_amdgcn_s_setprio(1);
    #pragma unroll
    for (int i = 0; i < 4; ++i)
      #pragma unroll
      for (int j = 0; j < 4; ++j)
        acc[i][j] = __builtin_amdgcn_mfma_f32_16x16x32_bf16(aF[i], bF[j], acc[i][j], 0, 0, 0);
    __builtin_amdgcn_s_setprio(0);
    __builtin_amdgcn_s_barrier();

    if (t + 3 < nt) stageB(t + 3, (t + 3) & 3);
    #pragma unroll
    for (int i = 4; i < 8; ++i) aF[i] = *(const short8*)(base + aOffB[i]);
    {
      int rem = nt - 1 - t;
      if (rem >= 3)      asm volatile("s_waitcnt vmcnt(8)" ::: "memory");
      else if (rem == 2) asm volatile("s_waitcnt vmcnt(4)" ::: "memory");
      else               asm volatile("s_waitcnt vmcnt(0)" ::: "memory");
    }
    __builtin_amdgcn_s_barrier();
    __builtin_amdgcn_s_setprio(1);
    #pragma unroll
    for (int i = 4; i < 8; ++i)
      #pragma unroll
      for (int j = 0; j < 4; ++j)
        acc[i][j] = __builtin_amdgcn_mfma_f32_16x16x32_bf16(aF[i], bF[j], acc[i][j], 0, 0, 0);
    __builtin_amdgcn_s_setprio(0);
    __builtin_amdgcn_s_barrier();
  }

  // Fused k-norm epilogue: this wave's cols bn+wn*64..+64 = head (bn>>6)+wn.
  const int hcol = (bn >> 6) + wn;
  float kb[4];
  #pragma unroll
  for (int j = 0; j < 4; ++j) kb[j] = bias[bn + wn * 64 + j * 16 + l15];
  #pragma unroll
  for (int i = 0; i < 8; ++i) {
    #pragma unroll
    for (int r = 0; r < 4; ++r) {
      float s = 0.0f;
      #pragma unroll
      for (int j = 0; j < 4; ++j) {
        float val = acc[i][j][r] + kb[j];
        s += val * val;
      }
      s += __shfl_xor(s, 1, 64);
      s += __shfl_xor(s, 2, 64);
      s += __shfl_xor(s, 4, 64);
      s += __shfl_xor(s, 8, 64);
      if (l15 == 0) {
        int row = bm + wm * 128 + i * 16 + sr * 4 + r;
        Cout[(size_t)row * 16 + hcol] = sqrtf(s);
      }
    }
  }
}

extern "C" void kernel_launch(void* const* d_in, const int* in_sizes, int n_in,
                              void* d_out, int out_size, void* d_ws, size_t ws_size,
                              hipStream_t stream) {
  const float* x    = (const float*)d_in[0];   // (4,8192,1024)
  const float* Wqkv = (const float*)d_in[1];   // (3072,1024)
  const float* bqkv = (const float*)d_in[2];   // (3072,)
  const float* Wout = (const float*)d_in[3];   // (1024,1024)
  const float* bout = (const float*)d_in[4];   // (1024,)
  float* out = (float*)d_out;                  // (4,8192,1024) f32

  const size_t M = (size_t)BB * NN;            // 32768

  // Workspace layout
  char* ws = (char*)d_ws;
  size_t off = 0;
  unsigned short* xb    = (unsigned short*)(ws + off); off += M * DD * 2;            // 64 MB
  unsigned short* wkb   = (unsigned short*)(ws + off); off += (size_t)DD * DD * 2;   // 2 MB
  unsigned short* wvb   = (unsigned short*)(ws + off); off += (size_t)DD * DD * 2;   // 2 MB
  unsigned short* woutb = (unsigned short*)(ws + off); off += (size_t)DD * DD * 2;   // 2 MB
  float*          kw    = (float*)(ws + off);          off += M * HH * 4;            // 2 MB
  unsigned short* xwb   = (unsigned short*)(ws + off); off += (size_t)HH*BB*GG*DD*2; // 64 MB
  float*          field2= (float*)(ws + off);          off += (size_t)BB*GG*DD*4;    // 8 MB
  unsigned short* fconv2= (unsigned short*)(ws + off); off += (size_t)BB*GG*DD*2;    // 4 MB
  float*          sw    = (float*)(ws + off);          off += (size_t)BB*GG*HH*4;    // 128 KB
  float* small = (float*)xb;   // 8 MB, aliases xb (dead after xw_kernel)

  // 1. bf16 conversions: x + Wk/Wv/Wout in one kernel
  cvt_all<<<8960, 256, 0, stream>>>(x, Wqkv, Wout, xb, wkb, wvb, woutb);

  // 2. kw[n,h] = ||x_n @ Wk_h^T + bk_h||  (fused epilogue; no k materialized)
  gemm_knorm<<<(DD / 256) * (M / 256), 512, 0, stream>>>(
      xb, wkb, bqkv + DD, kw, (int)M, DD, DD);

  // 3. xw[h,(b,g),:] = sum_{n in g} w * x[n,:]; sw = sum of weights
  xw_kernel<<<BB * GG, 256, 0, stream>>>(xb, kw, xwb, sw);

  // 4. field2[(b,g), h*64+d] = xw_h @ Wv_h^T + sw*bv
  field_gemm<<<HH * 32, 256, 0, stream>>>(xwb, wvb, sw, bqkv + 2 * DD, field2);

  // 5. circular conv along g -> bf16 (b*512+g, 1024)
  conv_kernel<<<BB * GG, 256, 0, stream>>>(field2, fconv2);

  // 6. small = fconv2 @ Wout^T + bout  (2048 x 1024 f32) — 64x64 tiles, 512 blocks
  gemm64<<<(BB * GG / 64) * (DD / 64), 256, 0, stream>>>(
      fconv2, woutb, bout, small, BB * GG, DD, DD);

  // 7. out[b,n,:] = small[(b,g(n)),:]
  expand_kernel<<<4096, 256, 0, stream>>>(small, out);
}